// Round 6
// baseline (44598.856 us; speedup 1.0000x reference)
//
#include <hip/hip_runtime.h>
#include <hip/hip_fp16.h>
#include <stdint.h>

// LSTM, E=2048, B=2, T=2048, ALL I/O float32 (per reference dtypes).
// For t>=1 input==h, so gates = h @ (W_ih+W_hh)^T + (b_ih+b_hh).
// v7: fused poll-compute + distributed tail; v4 poll cadence restored.
//  - v6 lesson: pipelined no-sleep polling REGRESSED (+0.5us/step) ->
//    exchange is fabric-contention-sensitive. Restore v4 cadence:
//    initial loads + vmcnt(0), then sleep(1) + exec-masked reload rounds.
//  - FUSION: each lane polls exactly the 8 h-values its own FMAs consume
//    (8 consecutive k, one batch = lane&1). On tag match, 32 FMAs fire
//    immediately (weights f16-packed: 32 rows x 8 k = 128 VGPR). Compute
//    hides inside the poll wait; NO hlds, NO deposits, NO lgkm sync.
//  - Poll loads are 4x dwordx4 per lane (2 chunks each): HALF the fabric
//    requests of v4/v6's 8x dwordx2. q = [pay0,tag0,pay1,tag1].
//  - Reduce: 31-shfl recursive halving over lane bits {5,4,3,2,1} (bit 0 =
//    batch, excluded). Lane ends with (row=(lane>>1)&31, b=lane&1) partial.
//  - pls: [2 parity][64 rb][9 pad] floats = 4.6 KB (bank-conflict-free).
//    ONE __syncthreads/step. Tail DISTRIBUTED: wave wv finishes element
//    e0+wv: per-gate nonlinearity in parallel lanes (tanh via 2*sig(2s)-1,
//    one transcendental), 3 shfl gathers, publish from lanes (g==1,w==0).
//  - Parity safety: publishes(t+1) happen after pls(t) reads (data dep);
//    poll(t+2) gated on publishes(t+2) -> 2-parity pls + 2-parity chk safe.
// Protocol: 8 B [tag|payload] chunks, sc0 sc1 LLC-direct both sides,
// tag-validated (poison 0xAAAAAAAA never matches tags 1..2047), relaxed.

#define E 2048
#define NBLK 256
#define NTHR 512
#define SMEM_MAIN 4608
#define SMEM_PROJ 131072

typedef uint32_t u32;
typedef unsigned long long u64;
typedef unsigned int u32x4 __attribute__((ext_vector_type(4)));

__device__ __forceinline__ float sigf(float x){
  return __builtin_amdgcn_rcpf(1.0f + __expf(-x));
}
__device__ __forceinline__ float tanhfast(float x){
  float e = __expf(2.0f * x);
  return 1.0f - 2.0f * __builtin_amdgcn_rcpf(e + 1.0f);
}

// tag-check + fused 32-FMA for chunk slot J (payload PAY, tag word TG)
#define CHKJ(J, PAY, TG) \
  if (pend & (1 << J)){ \
    if ((TG) == tag){ \
      const float h_ = __uint_as_float(PAY); \
      _Pragma("unroll") \
      for (int p = 0; p < 16; ++p){ \
        acc[2*p]   = fmaf(__low2float (wh[p*8 + J]), h_, acc[2*p]); \
        acc[2*p+1] = fmaf(__high2float(wh[p*8 + J]), h_, acc[2*p+1]); \
      } \
      pend &= ~(1 << J); \
    } \
  }

// initial 4x dwordx4: 8 chunks (lane-consecutive), LLC-direct
#define ISSUE4Q(Q0, Q1, Q2, Q3) \
  asm volatile( \
    "global_load_dwordx4 %0, %4, off sc0 sc1\n\t" \
    "global_load_dwordx4 %1, %4, off offset:16 sc0 sc1\n\t" \
    "global_load_dwordx4 %2, %4, off offset:32 sc0 sc1\n\t" \
    "global_load_dwordx4 %3, %4, off offset:48 sc0 sc1" \
    : "=&v"(Q0), "=&v"(Q1), "=&v"(Q2), "=&v"(Q3) \
    : "v"(src) : "memory")

// exec-masked reload of pair P (chunks 2P, 2P+1) if either pending
#define RELOADP(P, QP, OFS) \
  if (pend & (3 << (2*(P)))){ \
    asm volatile("global_load_dwordx4 %0, %1, off offset:" OFS " sc0 sc1" \
                 : "=v"(QP) : "v"(src) : "memory"); \
  }

// recursive-halving fold over lane bit MASK, acc count 2*HALF -> HALF
#define FOLD(MASK, HALF) \
  _Pragma("unroll") \
  for (int i = 0; i < HALF; ++i){ \
    float send_ = (lane & MASK) ? acc[i] : acc[i + HALF]; \
    float got_  = __shfl_xor(send_, MASK, 64); \
    acc[i] = ((lane & MASK) ? acc[i + HALF] : acc[i]) + got_; \
  }

__global__ void __launch_bounds__(NTHR, 1) lstm_kernel(
    const float* __restrict__ xin, const float* __restrict__ Wih,
    const float* __restrict__ Whh, const float* __restrict__ bih,
    const float* __restrict__ bhh, u64* __restrict__ chk,
    float* __restrict__ seqout)
{
  extern __shared__ char smem[];
  float* pls = (float*)smem;                   // [2][64][9] = 4608 B

  const int tid  = threadIdx.x;
  const int blk  = blockIdx.x;
  const int e0   = blk << 3;                   // this block owns h elems e0..e0+7
  const int lane = tid & 63;
  const int wv   = tid >> 6;                   // wave 0..7
  const int b    = lane & 1;                   // consumer batch (chunk bit 3)
  const int kbase = (wv << 8) + ((lane >> 1) << 3);  // lane's 8 consecutive k

  // ---- init: x slice, fp32 t=0 accumulation, f16 Wc packing ----
  float xv[8];
  #pragma unroll
  for (int j = 0; j < 8; ++j) xv[j] = xin[b * E + kbase + j];

  __half2 wh[128];                             // rows (2p,2p+1) x k (kbase+j)
  float acc[32];
  #pragma unroll
  for (int i = 0; i < 32; ++i) acc[i] = 0.0f;

  #pragma unroll
  for (int p = 0; p < 16; ++p){
    const int r0 = 2*p, r1 = 2*p + 1;
    const size_t g0 = ((size_t)(r0 >> 3) << 11) + e0 + (r0 & 7);
    const size_t g1 = ((size_t)(r1 >> 3) << 11) + e0 + (r1 & 7);
    const float* a0p = Wih + g0 * E + kbase;
    const float* a1p = Wih + g1 * E + kbase;
    const float* h0p = Whh + g0 * E + kbase;
    const float* h1p = Whh + g1 * E + kbase;
    #pragma unroll
    for (int j = 0; j < 8; ++j){
      const float a0 = a0p[j], a1 = a1p[j];
      acc[r0] = fmaf(a0, xv[j], acc[r0]);      // t=0: x @ W_ih^T, full fp32
      acc[r1] = fmaf(a1, xv[j], acc[r1]);
      wh[p*8 + j] = __halves2half2(__float2half_rn(a0 + h0p[j]),
                                   __float2half_rn(a1 + h1p[j]));
    }
  }

  // tail constants: lane handles (gate g, batch bb, wave-partial w)
  const int g  = lane >> 4;
  const int bb = (lane >> 3) & 1;
  const int w  = lane & 7;
  const size_t growt = ((size_t)g << 11) + e0 + wv;   // row = g*8 + wv
  const float br = bih[growt] + bhh[growt];
  float creg = 0.0f;                           // cell state (g==1 lanes)

  // pls addressing (stride 9 floats -> conflict-free)
  const int rb = (((lane >> 1) & 31) << 1) | b;       // fold output identity
  float* const plsw = pls + rb * 9 + wv;              // + parity*576
  const int rdofs = ((g * 8 + wv) * 2 + bb) * 9 + w;  // + parity*576

  u64* const pchk0 = chk;                      // parity 0 base
  u64* const pchk1 = chk + 4096;               // parity 1 base

  for (int t = 0; t < 2048; ++t){
    // ---- in-wave fold: acc[32] -> acc[0] = (row,b) wave-partial ----
    FOLD(32, 16) FOLD(16, 8) FOLD(8, 4) FOLD(4, 2) FOLD(2, 1)
    plsw[(t & 1) * 576] = acc[0];
    __syncthreads();                           // the ONLY barrier per step

    // ---- distributed tail: wave wv finishes element e0+wv ----
    {
      float s = pls[(t & 1) * 576 + rdofs];
      s += __shfl_xor(s, 1, 64);
      s += __shfl_xor(s, 2, 64);
      s += __shfl_xor(s, 4, 64);               // sum 8 wave-partials
      s += br;
      // gate nonlinearity in parallel: tanh(s) = 2*sig(2s) - 1 (g==2)
      const float arg = (g == 2) ? (s + s) : s;
      const float t0 = sigf(arg);
      const float nl = (g == 2) ? (2.0f * t0 - 1.0f) : t0;
      const float SI = __shfl(nl, (lane + 48) & 63, 64);  // gate i (g-16)
      const float TG = __shfl(nl, (lane + 16) & 63, 64);  // gate g (g+16)
      const float SO = __shfl(nl, (lane + 32) & 63, 64);  // gate o (g+32)
      const float cn = nl * creg + SI * TG;    // valid on g==1 (nl = sig(f))
      const float hn = SO * tanhfast(cn);
      creg = cn;                               // meaningful on g==1 only
      if (g == 1 && w == 0){
        if (t < 2047){                         // publish FIRST (critical path)
          const u64 pk = ((u64)(u32)(t + 1) << 32) | (u64)__float_as_uint(hn);
          u64* dst = (((t + 1) & 1) ? pchk1 : pchk0) + (blk << 4) + (bb << 3) + wv;
          asm volatile("global_store_dwordx2 %0, %1, off sc0 sc1"
                       :: "v"(dst), "v"(pk) : "memory");
        }
        seqout[((size_t)bb * 2048 + (size_t)t) * E + e0 + wv] = hn;
      }
    }
    if (t == 2047) break;

    // ---- poll tag t+1 with fused FMA (v4 cadence: sleep + masked reload) --
    #pragma unroll
    for (int i = 0; i < 32; ++i) acc[i] = 0.0f;
    {
      const u64* src = (((t + 1) & 1) ? pchk1 : pchk0) + (wv << 9) + (lane << 3);
      const u32 tag = (u32)(t + 1);
      u32x4 q0, q1, q2, q3;
      ISSUE4Q(q0, q1, q2, q3);
      asm volatile("s_waitcnt vmcnt(0)" ::: "memory");
      int pend = 0xFF;
      for (;;){
        CHKJ(0, q0.x, q0.y) CHKJ(1, q0.z, q0.w)
        CHKJ(2, q1.x, q1.y) CHKJ(3, q1.z, q1.w)
        CHKJ(4, q2.x, q2.y) CHKJ(5, q2.z, q2.w)
        CHKJ(6, q3.x, q3.y) CHKJ(7, q3.z, q3.w)
        if (!pend) break;
        __builtin_amdgcn_s_sleep(1);
        RELOADP(0, q0, "0")  RELOADP(1, q1, "16")
        RELOADP(2, q2, "32") RELOADP(3, q3, "48")
        asm volatile("s_waitcnt vmcnt(0)" ::: "memory");
      }
    }
  }
}

// In-place projection: out[row][n] = sum_k h[row][k]*Wout[n][k] + bout[n].
// Block owns 16 rows, staged to LDS first. 2 n-columns per pass halves the
// LDS read instruction count (proj is LDS-issue-bound at 1 wave/SIMD).
__global__ void __launch_bounds__(256, 1) proj_kernel(
    float* __restrict__ io, const float* __restrict__ Wout,
    const float* __restrict__ bout)
{
  extern __shared__ char smem[];
  float* alds = (float*)smem;                  // 16 x 2048 fp32 = 131072 B
  const int tid = threadIdx.x;
  const size_t rbase = (size_t)blockIdx.x * 16 * E;

  for (int idx = tid; idx < 8192; idx += 256){
    float4 v = *(const float4*)(io + rbase + ((size_t)idx << 2));
    *(float4*)(alds + (idx << 2)) = v;
  }
  __syncthreads();

  for (int p = 0; p < 4; ++p){
    const int n0 = (p << 8) + tid;             // column pair: n0, n0+1024
    const int n1 = n0 + 1024;
    const float* wr0 = Wout + (size_t)n0 * E;
    const float* wr1 = Wout + (size_t)n1 * E;
    float acc0[16], acc1[16];
    #pragma unroll
    for (int m = 0; m < 16; ++m){ acc0[m] = 0.0f; acc1[m] = 0.0f; }
    for (int kc = 0; kc < 256; ++kc){
      const float4 a0v = *(const float4*)(wr0 + (kc << 3));
      const float4 a1v = *(const float4*)(wr0 + (kc << 3) + 4);
      const float4 b0v = *(const float4*)(wr1 + (kc << 3));
      const float4 b1v = *(const float4*)(wr1 + (kc << 3) + 4);
      const float* ap = alds + (kc << 3);
      #pragma unroll
      for (int m = 0; m < 16; ++m){
        const float* a = ap + (m << 11);
        float4 x0 = *(const float4*)(a);
        float4 x1 = *(const float4*)(a + 4);
        acc0[m] = fmaf(a0v.x, x0.x, acc0[m]); acc0[m] = fmaf(a0v.y, x0.y, acc0[m]);
        acc0[m] = fmaf(a0v.z, x0.z, acc0[m]); acc0[m] = fmaf(a0v.w, x0.w, acc0[m]);
        acc0[m] = fmaf(a1v.x, x1.x, acc0[m]); acc0[m] = fmaf(a1v.y, x1.y, acc0[m]);
        acc0[m] = fmaf(a1v.z, x1.z, acc0[m]); acc0[m] = fmaf(a1v.w, x1.w, acc0[m]);
        acc1[m] = fmaf(b0v.x, x0.x, acc1[m]); acc1[m] = fmaf(b0v.y, x0.y, acc1[m]);
        acc1[m] = fmaf(b0v.z, x0.z, acc1[m]); acc1[m] = fmaf(b0v.w, x0.w, acc1[m]);
        acc1[m] = fmaf(b1v.x, x1.x, acc1[m]); acc1[m] = fmaf(b1v.y, x1.y, acc1[m]);
        acc1[m] = fmaf(b1v.z, x1.z, acc1[m]); acc1[m] = fmaf(b1v.w, x1.w, acc1[m]);
      }
    }
    const float bo0 = bout[n0];
    const float bo1 = bout[n1];
    #pragma unroll
    for (int m = 0; m < 16; ++m){
      io[rbase + ((size_t)m << 11) + n0] = acc0[m] + bo0;
      io[rbase + ((size_t)m << 11) + n1] = acc1[m] + bo1;
    }
  }
}

extern "C" void kernel_launch(void* const* d_in, const int* in_sizes, int n_in,
                              void* d_out, int out_size, void* d_ws, size_t ws_size,
                              hipStream_t stream)
{
  const float* xin  = (const float*)d_in[0];
  const float* Wih  = (const float*)d_in[1];
  const float* Whh  = (const float*)d_in[2];
  const float* bih  = (const float*)d_in[3];
  const float* bhh  = (const float*)d_in[4];
  const float* Wout = (const float*)d_in[5];
  const float* bout = (const float*)d_in[6];
  float* out = (float*)d_out;

  // chunk buffer: 2 parities x 4096 chunks x 8 B = 64 KB.
  // Poison 0xAAAAAAAA is never a valid tag (tags are 1..2047) -> no init pass.
  u64* chk = (u64*)d_ws;

  hipFuncSetAttribute((const void*)lstm_kernel,
                      hipFuncAttributeMaxDynamicSharedMemorySize, SMEM_MAIN);
  hipFuncSetAttribute((const void*)proj_kernel,
                      hipFuncAttributeMaxDynamicSharedMemorySize, SMEM_PROJ);

  void* args[] = { (void*)&xin, (void*)&Wih, (void*)&Whh, (void*)&bih, (void*)&bhh,
                   (void*)&chk, (void*)&out };
  hipLaunchCooperativeKernel((const void*)lstm_kernel, dim3(NBLK), dim3(NTHR),
                             args, SMEM_MAIN, stream);

  proj_kernel<<<256, 256, SMEM_PROJ, stream>>>(out, Wout, bout);
}

// Round 8
// 12885.016 us; speedup vs baseline: 3.4613x; 3.4613x over previous
//
#include <hip/hip_runtime.h>
#include <hip/hip_fp16.h>
#include <stdint.h>

// LSTM, E=2048, B=2, T=2048, ALL I/O float32 (per reference dtypes).
// For t>=1 input==h, so gates = h @ (W_ih+W_hh)^T + (b_ih+b_hh).
// v9 = v8 with the proj staging-loop bound FIXED (16384 -> 32768).
//   v8 failure (absmax 8.0): only rows 0-15 of each 32-row block were
//   staged to LDS (65536 floats = 32768 packed u32, loop stopped at
//   16384); rows 16-31 computed from uninitialized LDS. lstm tail port
//   re-verified by derivation -- unchanged.
// v8 = v4 (anchor, 7518us) + v7's DISTRIBUTED TAIL + 32-row f16-staged proj.
//  - v7 post-mortem: 512-thr blocks are HARD-CAPPED at 128 VGPRs by the
//    allocator (v2 and v7 both spilled at demand ~190). Fused poll-compute
//    needs >=128 weight regs + acc -> infeasible. Abandoned.
//  - Distributed tail (verified correct in v7): after the barrier, wave wv
//    finishes element e0+wv itself: 1 pls dword read (lane = g*16+bb*8+w),
//    3 shfl-xor adds over w, ONE transcendental per lane (tanh(s) =
//    2*sig(2s)-1 for the g-gate), 3 shfl gathers, publish from 8 waves in
//    parallel. Replaces v4's wave0-serial tail (~500cy -> ~300cy) and
//    publishes ~200cy earlier.
//  - pls: [2 parity][32 rows][18] floats (stride 18 -> float2-aligned,
//    <=2-way bank aliasing = free). 4.6 KB total.
// Kept from v4 verbatim: f16 packed weights in VGPRs (v_fma_mix), fp32 h in
// padded LDS (stride 36), wave-local poll slice, v4 poll cadence (initial
// vmcnt(0) + sleep(1) + exec-masked per-slot reload -- v6 proved pipelined
// no-sleep polling regresses), lgkmcnt-only deposit sync, ONE
// __syncthreads/step, c-state in registers, sc0 sc1 LLC-direct exchange,
// publish-before-seqout. Protocol: 8 B [tag|payload] chunks, tag-validated
// (poison 0xAAAAAAAA never matches tags 1..2047), relaxed, no fences.

#define E 2048
#define NBLK 256
#define NTHR 512
#define HLDS_B 2304            // padded floats per batch: 64 slices * 36
#define PLS_PAR 576            // floats per parity: 32 rows * 18
#define SMEM_MAIN 23040
#define SMEM_PROJ 131072

typedef uint32_t u32;
typedef unsigned long long u64;

__device__ __forceinline__ float sigf(float x){
  return __builtin_amdgcn_rcpf(1.0f + __expf(-x));
}
__device__ __forceinline__ float tanhfast(float x){
  // 1 - 2/(e^{2x}+1); exp overflow -> rcp(inf)=0 -> 1; underflow -> -1.
  float e = __expf(2.0f * x);
  return 1.0f - 2.0f * __builtin_amdgcn_rcpf(e + 1.0f);
}

// one row x 8 k, both batches: 16 FMAs from 4 packed-f16 weight pairs
#define ROWFMA8(W0, W1, W2, W3, A0, A1) \
  A0 = fmaf(__low2float(W0),  p0.x, A0); A0 = fmaf(__high2float(W0), p0.y, A0); \
  A0 = fmaf(__low2float(W1),  p0.z, A0); A0 = fmaf(__high2float(W1), p0.w, A0); \
  A0 = fmaf(__low2float(W2),  p1.x, A0); A0 = fmaf(__high2float(W2), p1.y, A0); \
  A0 = fmaf(__low2float(W3),  p1.z, A0); A0 = fmaf(__high2float(W3), p1.w, A0); \
  A1 = fmaf(__low2float(W0),  q0.x, A1); A1 = fmaf(__high2float(W0), q0.y, A1); \
  A1 = fmaf(__low2float(W1),  q0.z, A1); A1 = fmaf(__high2float(W1), q0.w, A1); \
  A1 = fmaf(__low2float(W2),  q1.x, A1); A1 = fmaf(__high2float(W2), q1.y, A1); \
  A1 = fmaf(__low2float(W3),  q1.z, A1); A1 = fmaf(__high2float(W3), q1.w, A1);

// tag-check + fp32 LDS-deposit for poll slot J (UJ: sampled u64 register)
#define POLLCHK(J, UJ) \
  if (pend & (1 << J)){ \
    if ((u32)(UJ >> 32) == tag){ \
      hlds[cdst[J]] = __uint_as_float((u32)UJ); \
      pend &= ~(1 << J); \
    } \
  }

// 8 LLC-direct samples of this lane's 8 poll slots (512 B stride per slot set)
#define ISSUE8(R0, R1, R2, R3, R4, R5, R6, R7) \
  asm volatile( \
    "global_load_dwordx2 %0, %8, off sc0 sc1\n\t" \
    "global_load_dwordx2 %1, %8, off offset:512 sc0 sc1\n\t" \
    "global_load_dwordx2 %2, %8, off offset:1024 sc0 sc1\n\t" \
    "global_load_dwordx2 %3, %8, off offset:1536 sc0 sc1\n\t" \
    "global_load_dwordx2 %4, %8, off offset:2048 sc0 sc1\n\t" \
    "global_load_dwordx2 %5, %8, off offset:2560 sc0 sc1\n\t" \
    "global_load_dwordx2 %6, %8, off offset:3072 sc0 sc1\n\t" \
    "global_load_dwordx2 %7, %8, off offset:3584 sc0 sc1" \
    : "=&v"(R0), "=&v"(R1), "=&v"(R2), "=&v"(R3), \
      "=&v"(R4), "=&v"(R5), "=&v"(R6), "=&v"(R7) \
    : "v"(src) : "memory")

// LLC-direct reload of slot J (exec-masked by the pend predicate)
#define RELOAD(J, UJ, OFS) \
  if (pend & (1 << J)){ \
    asm volatile("global_load_dwordx2 %0, %1, off offset:" OFS " sc0 sc1" \
                 : "=v"(UJ) : "v"(src) : "memory"); \
  }

__global__ void __launch_bounds__(NTHR, 1) lstm_kernel(
    const float* __restrict__ xin, const float* __restrict__ Wih,
    const float* __restrict__ Whh, const float* __restrict__ bih,
    const float* __restrict__ bhh, u64* __restrict__ chk,
    float* __restrict__ seqout)
{
  extern __shared__ char smem[];
  float* hlds = (float*)smem;                    // [2][2304] = 18432 B (padded h)
  float* pls  = (float*)(smem + 18432);          // [2][576]  =  4608 B partials

  const int tid  = threadIdx.x;
  const int blk  = blockIdx.x;
  const int e0   = blk << 3;                     // this block owns h elems e0..e0+7
  const int lane = tid & 63;
  const int wv   = tid >> 6;                     // wave 0..7, k-slice [wv*256, +256)
  const int rg   = lane >> 3;                    // row group: rows rg*4..rg*4+3
  const int ksl  = lane & 7;                     // 32-k sub-slice within wave
  const int ks   = (wv << 3) + ksl;              // global 32-k slice 0..63
  const int k0   = ks << 5;

  // x for t=0, written in the padded h layout
  for (int i = tid; i < 2 * E; i += NTHR){
    const int b = i >> 11, k = i & 2047;
    hlds[b * HLDS_B + (k >> 5) * 36 + (k & 31)] = xin[i];
  }
  __syncthreads();

  const float* hb0 = hlds + ks * 36;             // batch 0, own 32-k slice
  const float* hb1 = hlds + HLDS_B + ks * 36;    // batch 1

  // ---- fused: build f16 Wc = Wih + Whh into registers (64 half2) AND
  //      compute t=0 gates = x @ W_ih^T in full fp32 (h=0 at t=0) ----
  __half2 wh[64];
  float acc0[4] = {0.f, 0.f, 0.f, 0.f};
  float acc1[4] = {0.f, 0.f, 0.f, 0.f};
  #pragma unroll
  for (int rr = 0; rr < 4; ++rr){
    const int row  = (rg << 2) + rr;             // 0..31 = gate*8 + eoff
    const int grow = ((row >> 3) << 11) + e0 + (row & 7);
    const float* pa = Wih + (size_t)grow * E + k0;
    const float* pb = Whh + (size_t)grow * E + k0;
    #pragma unroll
    for (int c = 0; c < 8; ++c){                 // 4 k per chunk
      float4 a = *(const float4*)(pa + (c << 2));
      float4 b = *(const float4*)(pb + (c << 2));
      wh[(rr << 4) + (c << 1)    ] =
        __halves2half2(__float2half_rn(a.x + b.x), __float2half_rn(a.y + b.y));
      wh[(rr << 4) + (c << 1) + 1] =
        __halves2half2(__float2half_rn(a.z + b.z), __float2half_rn(a.w + b.w));
      float4 x0 = *(const float4*)(hb0 + (c << 2));
      float4 x1 = *(const float4*)(hb1 + (c << 2));
      acc0[rr] = fmaf(a.x, x0.x, acc0[rr]); acc0[rr] = fmaf(a.y, x0.y, acc0[rr]);
      acc0[rr] = fmaf(a.z, x0.z, acc0[rr]); acc0[rr] = fmaf(a.w, x0.w, acc0[rr]);
      acc1[rr] = fmaf(a.x, x1.x, acc1[rr]); acc1[rr] = fmaf(a.y, x1.y, acc1[rr]);
      acc1[rr] = fmaf(a.z, x1.z, acc1[rr]); acc1[rr] = fmaf(a.w, x1.w, acc1[rr]);
    }
  }

  // distributed-tail constants: lane = g*16 + bb*8 + w handles
  // (gate g, batch bb, wave-partial w) of element e0+wv (row = g*8 + wv)
  const int g  = lane >> 4;
  const int bb = (lane >> 3) & 1;
  const int w  = lane & 7;
  const size_t growt = ((size_t)g << 11) + e0 + wv;
  const float br = bih[growt] + bhh[growt];
  float creg = 0.0f;                             // cell state (g==1 lanes)

  // wave-local poll mapping: chunk c = wv*512 + j*64 + lane, so load j is a
  // 512 B contiguous wave read (full 64 B lines -> no fetch amplification).
  // chunk c (block-relative): b=(c>>3)&1, elem e=((c>>4)<<3)|(c&7)
  int cdst[8];
  #pragma unroll
  for (int j = 0; j < 8; ++j){
    const int c = (wv << 9) + (j << 6) + lane;
    const int b = (c >> 3) & 1;
    const int e = ((c >> 4) << 3) | (c & 7);
    cdst[j] = b * HLDS_B + (e >> 5) * 36 + (e & 31);
  }
  u64* const pchk0 = chk;                        // parity 0 base
  u64* const pchk1 = chk + 4096;                 // parity 1 base

  for (int t = 0; t < 2048; ++t){
    // wave-level pre-reduce across the 8 k-sub-slices (ksl = lane bits 0..2)
    #pragma unroll
    for (int m = 1; m <= 4; m <<= 1){
      #pragma unroll
      for (int rr = 0; rr < 4; ++rr){
        acc0[rr] += __shfl_xor(acc0[rr], m, 64);
        acc1[rr] += __shfl_xor(acc1[rr], m, 64);
      }
    }
    if (ksl == 0){                               // 8 lanes/wave publish partials
      float* pw = pls + (t & 1) * PLS_PAR;
      #pragma unroll
      for (int rr = 0; rr < 4; ++rr)
        *(float2*)(pw + ((rg << 2) + rr) * 18 + (wv << 1)) =
          make_float2(acc0[rr], acc1[rr]);
    }
    __syncthreads();                             // the ONLY barrier per step

    // ---- distributed tail: wave wv finishes element e0+wv (v7-verified) --
    {
      float s = pls[(t & 1) * PLS_PAR + ((g << 3) + wv) * 18 + (w << 1) + bb];
      s += __shfl_xor(s, 1, 64);
      s += __shfl_xor(s, 2, 64);
      s += __shfl_xor(s, 4, 64);                 // sum 8 wave-partials
      s += br;
      // gate nonlinearity in parallel: tanh(s) = 2*sig(2s) - 1 (g==2)
      const float arg = (g == 2) ? (s + s) : s;
      const float t0v = sigf(arg);
      const float nl = (g == 2) ? (2.0f * t0v - 1.0f) : t0v;
      const float SI = __shfl(nl, (lane + 48) & 63, 64);  // gate i
      const float TG = __shfl(nl, (lane + 16) & 63, 64);  // gate g
      const float SO = __shfl(nl, (lane + 32) & 63, 64);  // gate o
      const float cn = nl * creg + SI * TG;      // valid on g==1 (nl = sig(f))
      const float hn = SO * tanhfast(cn);
      creg = cn;                                 // meaningful on g==1 only
      if (g == 1 && w == 0){
        if (t < 2047){                           // publish FIRST (critical path)
          const u64 pk = ((u64)(u32)(t + 1) << 32) | (u64)__float_as_uint(hn);
          u64* dst = (((t + 1) & 1) ? pchk1 : pchk0) + (blk << 4) + (bb << 3) + wv;
          asm volatile("global_store_dwordx2 %0, %1, off sc0 sc1"
                       :: "v"(dst), "v"(pk) : "memory");
        }
        seqout[(((size_t)bb << 11) + (size_t)t) * E + e0 + wv] = hn;
      }
    }
    if (t == 2047) break;

    {                                            // v4 poll: LLC-direct + sleep
      const u64* src = (((t + 1) & 1) ? pchk1 : pchk0) + (wv << 9) + lane;
      const u32 tag = (u32)(t + 1);
      u64 a0_, a1_, a2_, a3_, a4_, a5_, a6_, a7_;
      ISSUE8(a0_, a1_, a2_, a3_, a4_, a5_, a6_, a7_);
      asm volatile("s_waitcnt vmcnt(0)" ::: "memory");
      int pend = 0xFF;
      while (true){
        POLLCHK(0, a0_) POLLCHK(1, a1_) POLLCHK(2, a2_) POLLCHK(3, a3_)
        POLLCHK(4, a4_) POLLCHK(5, a5_) POLLCHK(6, a6_) POLLCHK(7, a7_)
        if (pend == 0) break;
        __builtin_amdgcn_s_sleep(1);
        RELOAD(0, a0_, "0")    RELOAD(1, a1_, "512")
        RELOAD(2, a2_, "1024") RELOAD(3, a3_, "1536")
        RELOAD(4, a4_, "2048") RELOAD(5, a5_, "2560")
        RELOAD(6, a6_, "3072") RELOAD(7, a7_, "3584")
        asm volatile("s_waitcnt vmcnt(0)" ::: "memory");
      }
      // own ds_writes visible to all lanes of this wave (wave-synchronous)
      asm volatile("s_waitcnt lgkmcnt(0)" ::: "memory");
      __builtin_amdgcn_sched_barrier(0);
    }

    // compute acc(t+1): h @ Wc^T, weights in f16 registers
    #pragma unroll
    for (int rr = 0; rr < 4; ++rr){ acc0[rr] = 0.f; acc1[rr] = 0.f; }
    #pragma unroll
    for (int c8 = 0; c8 < 4; ++c8){              // 8 k per chunk
      float4 p0 = *(const float4*)(hb0 + (c8 << 3));
      float4 p1 = *(const float4*)(hb0 + (c8 << 3) + 4);
      float4 q0 = *(const float4*)(hb1 + (c8 << 3));
      float4 q1 = *(const float4*)(hb1 + (c8 << 3) + 4);
      #pragma unroll
      for (int rr = 0; rr < 4; ++rr){
        ROWFMA8(wh[(rr << 4) + (c8 << 2)],     wh[(rr << 4) + (c8 << 2) + 1],
                wh[(rr << 4) + (c8 << 2) + 2], wh[(rr << 4) + (c8 << 2) + 3],
                acc0[rr], acc1[rr]);
      }
    }
  }
}

// In-place projection: out[row][n] = sum_k h[row][k]*Wout[n][k] + bout[n].
// v9: 128 blocks x 512 thr, 32 rows/block staged as F16 in LDS (128 KB).
// Wout traffic halves: 4.3 GB -> 2.05 GB (proj is Wout-traffic-bound at
// ~4.7 TB/s effective). f16 staging is ONE-SHOT quantization (no
// recurrence; v5's compounding failure mode doesn't apply): error ~1e-4.
// Rows exclusive per block + single stage before any writes -> race-free.
// v8 bug fixed: stage loop bound is 32768 packed u32 (32 rows x 1024),
// not 16384 (which left rows 16-31 uninitialized -> absmax 8.0).
__global__ void __launch_bounds__(512, 1) proj_kernel(
    float* __restrict__ io, const float* __restrict__ Wout,
    const float* __restrict__ bout)
{
  extern __shared__ char smem[];
  u32* ah = (u32*)smem;                        // [32 rows][1024] half2 = 128 KB
  const int tid = threadIdx.x;
  const size_t rbase = (size_t)blockIdx.x * 32 * E;

  for (int idx = tid; idx < 32768; idx += 512){   // 32*2048 halves / 2
    const float2 v = *(const float2*)(io + rbase + ((size_t)idx << 1));
    ah[idx] = (u32)__half_as_ushort(__float2half_rn(v.x))
            | ((u32)__half_as_ushort(__float2half_rn(v.y)) << 16);
  }
  __syncthreads();

  for (int p = 0; p < 2; ++p){
    const int n0 = (p << 9) + tid;             // column pair: n0, n0+1024
    const int n1 = n0 + 1024;
    const float* wr0 = Wout + (size_t)n0 * E;
    const float* wr1 = Wout + (size_t)n1 * E;
    float acc0[32], acc1[32];
    #pragma unroll
    for (int m = 0; m < 32; ++m){ acc0[m] = 0.0f; acc1[m] = 0.0f; }
    for (int kc = 0; kc < 256; ++kc){          // 8 k per iter
      const float4 a0v = *(const float4*)(wr0 + (kc << 3));
      const float4 a1v = *(const float4*)(wr0 + (kc << 3) + 4);
      const float4 b0v = *(const float4*)(wr1 + (kc << 3));
      const float4 b1v = *(const float4*)(wr1 + (kc << 3) + 4);
      const u32* hp = ah + (kc << 2);
      #pragma unroll
      for (int m = 0; m < 32; ++m){
        const uint4 hv = *(const uint4*)(hp + (m << 10));  // 8 halves, bcast
        const __half2 h0 = __builtin_bit_cast(__half2, hv.x);
        const __half2 h1 = __builtin_bit_cast(__half2, hv.y);
        const __half2 h2 = __builtin_bit_cast(__half2, hv.z);
        const __half2 h3 = __builtin_bit_cast(__half2, hv.w);
        acc0[m] = fmaf(a0v.x, __low2float(h0),  acc0[m]);
        acc0[m] = fmaf(a0v.y, __high2float(h0), acc0[m]);
        acc0[m] = fmaf(a0v.z, __low2float(h1),  acc0[m]);
        acc0[m] = fmaf(a0v.w, __high2float(h1), acc0[m]);
        acc0[m] = fmaf(a1v.x, __low2float(h2),  acc0[m]);
        acc0[m] = fmaf(a1v.y, __high2float(h2), acc0[m]);
        acc0[m] = fmaf(a1v.z, __low2float(h3),  acc0[m]);
        acc0[m] = fmaf(a1v.w, __high2float(h3), acc0[m]);
        acc1[m] = fmaf(b0v.x, __low2float(h0),  acc1[m]);
        acc1[m] = fmaf(b0v.y, __high2float(h0), acc1[m]);
        acc1[m] = fmaf(b0v.z, __low2float(h1),  acc1[m]);
        acc1[m] = fmaf(b0v.w, __high2float(h1), acc1[m]);
        acc1[m] = fmaf(b1v.x, __low2float(h2),  acc1[m]);
        acc1[m] = fmaf(b1v.y, __high2float(h2), acc1[m]);
        acc1[m] = fmaf(b1v.z, __low2float(h3),  acc1[m]);
        acc1[m] = fmaf(b1v.w, __high2float(h3), acc1[m]);
      }
    }
    const float bo0 = bout[n0];
    const float bo1 = bout[n1];
    #pragma unroll
    for (int m = 0; m < 32; ++m){
      io[rbase + ((size_t)m << 11) + n0] = acc0[m] + bo0;
      io[rbase + ((size_t)m << 11) + n1] = acc1[m] + bo1;
    }
  }
}

extern "C" void kernel_launch(void* const* d_in, const int* in_sizes, int n_in,
                              void* d_out, int out_size, void* d_ws, size_t ws_size,
                              hipStream_t stream)
{
  const float* xin  = (const float*)d_in[0];
  const float* Wih  = (const float*)d_in[1];
  const float* Whh  = (const float*)d_in[2];
  const float* bih  = (const float*)d_in[3];
  const float* bhh  = (const float*)d_in[4];
  const float* Wout = (const float*)d_in[5];
  const float* bout = (const float*)d_in[6];
  float* out = (float*)d_out;

  // chunk buffer: 2 parities x 4096 chunks x 8 B = 64 KB.
  // Poison 0xAAAAAAAA is never a valid tag (tags are 1..2047) -> no init pass.
  u64* chk = (u64*)d_ws;

  hipFuncSetAttribute((const void*)lstm_kernel,
                      hipFuncAttributeMaxDynamicSharedMemorySize, SMEM_MAIN);
  hipFuncSetAttribute((const void*)proj_kernel,
                      hipFuncAttributeMaxDynamicSharedMemorySize, SMEM_PROJ);

  void* args[] = { (void*)&xin, (void*)&Wih, (void*)&Whh, (void*)&bih, (void*)&bhh,
                   (void*)&chk, (void*)&out };
  hipLaunchCooperativeKernel((const void*)lstm_kernel, dim3(NBLK), dim3(NTHR),
                             args, SMEM_MAIN, stream);

  proj_kernel<<<128, 512, SMEM_PROJ, stream>>>(out, Wout, bout);
}

// Round 9
// 8163.380 us; speedup vs baseline: 5.4633x; 1.5784x over previous
//
#include <hip/hip_runtime.h>
#include <hip/hip_fp16.h>
#include <stdint.h>

// LSTM, E=2048, B=2, T=2048, ALL I/O float32 (per reference dtypes).
// For t>=1 input==h, so gates = h @ (W_ih+W_hh)^T + (b_ih+b_hh).
// v10 = lstm: v4 BYTE-EXACT revert (anchor 7518us, proven twice)
//     + proj: 2 passes x 4 cols (halves LDS b128 issue, the real binding
//       term -- v9 post-mortem).
// v9 lessons recorded:
//  - Publish must be ONE coalesced wave-instruction. v9's distributed tail
//    issued 16 separate 8B sc0sc1 stores (8 waves) instead of wave0's
//    single 128B store -> consumer waits on the LAST of 16 fabric writes;
//    scattered 4B seqout stores additionally forced HBM RMW fills
//    (WRITE 98->295MB, FETCH 768MB->1.16GB). lstm +2us/step. REVERTED.
//  - proj is LDS-ISSUE-bound (broadcast b128 reads ~12cy each), not
//    HBM-bound: v9's 128-block f16 variant doubled per-CU issue with half
//    the machine idle -> 915->1270us. Fix is fewer LDS reads per FMA.
// v4 lstm (kept verbatim): f16 packed weights in VGPRs (v_fma_mix), fp32 h
// in padded LDS (stride 36), wave-local poll slice, poll cadence = initial
// vmcnt(0) + sleep(1) + exec-masked per-slot reload (v6 proved pipelined
// no-sleep polling regresses; fabric/LLC contention-sensitive), lgkmcnt-only
// deposit sync, ONE __syncthreads/step, wave0 tail with single coalesced
// publish, c-state in registers, sc0 sc1 LLC-direct exchange,
// publish-before-seqout, fast sigmoid/tanh. Protocol: 8B [tag|payload]
// chunks, tag-validated (poison 0xAAAAAAAA never matches tags 1..2047).

#define E 2048
#define NBLK 256
#define NTHR 512
#define HLDS_B 2304            // padded floats per batch: 64 slices * 36
#define PLS_STRIDE 20          // floats per row slot (16 used + 4 pad)
#define PLS_PAR 640            // floats per parity: 32 rows * 20
#define SMEM_MAIN 23680
#define SMEM_PROJ 131072

typedef uint32_t u32;
typedef unsigned long long u64;

__device__ __forceinline__ float sigf(float x){
  return __builtin_amdgcn_rcpf(1.0f + __expf(-x));
}
__device__ __forceinline__ float tanhfast(float x){
  // 1 - 2/(e^{2x}+1); exp overflow -> rcp(inf)=0 -> 1; underflow -> -1.
  float e = __expf(2.0f * x);
  return 1.0f - 2.0f * __builtin_amdgcn_rcpf(e + 1.0f);
}

// one row x 8 k, both batches: 16 FMAs from 4 packed-f16 weight pairs
#define ROWFMA8(W0, W1, W2, W3, A0, A1) \
  A0 = fmaf(__low2float(W0),  p0.x, A0); A0 = fmaf(__high2float(W0), p0.y, A0); \
  A0 = fmaf(__low2float(W1),  p0.z, A0); A0 = fmaf(__high2float(W1), p0.w, A0); \
  A0 = fmaf(__low2float(W2),  p1.x, A0); A0 = fmaf(__high2float(W2), p1.y, A0); \
  A0 = fmaf(__low2float(W3),  p1.z, A0); A0 = fmaf(__high2float(W3), p1.w, A0); \
  A1 = fmaf(__low2float(W0),  q0.x, A1); A1 = fmaf(__high2float(W0), q0.y, A1); \
  A1 = fmaf(__low2float(W1),  q0.z, A1); A1 = fmaf(__high2float(W1), q0.w, A1); \
  A1 = fmaf(__low2float(W2),  q1.x, A1); A1 = fmaf(__high2float(W2), q1.y, A1); \
  A1 = fmaf(__low2float(W3),  q1.z, A1); A1 = fmaf(__high2float(W3), q1.w, A1);

// tag-check + fp32 LDS-deposit for poll slot J (UJ: sampled u64 register)
#define POLLCHK(J, UJ) \
  if (pend & (1 << J)){ \
    if ((u32)(UJ >> 32) == tag){ \
      hlds[cdst[J]] = __uint_as_float((u32)UJ); \
      pend &= ~(1 << J); \
    } \
  }

// 8 LLC-direct samples of this lane's 8 poll slots (512 B stride per slot set)
#define ISSUE8(R0, R1, R2, R3, R4, R5, R6, R7) \
  asm volatile( \
    "global_load_dwordx2 %0, %8, off sc0 sc1\n\t" \
    "global_load_dwordx2 %1, %8, off offset:512 sc0 sc1\n\t" \
    "global_load_dwordx2 %2, %8, off offset:1024 sc0 sc1\n\t" \
    "global_load_dwordx2 %3, %8, off offset:1536 sc0 sc1\n\t" \
    "global_load_dwordx2 %4, %8, off offset:2048 sc0 sc1\n\t" \
    "global_load_dwordx2 %5, %8, off offset:2560 sc0 sc1\n\t" \
    "global_load_dwordx2 %6, %8, off offset:3072 sc0 sc1\n\t" \
    "global_load_dwordx2 %7, %8, off offset:3584 sc0 sc1" \
    : "=&v"(R0), "=&v"(R1), "=&v"(R2), "=&v"(R3), \
      "=&v"(R4), "=&v"(R5), "=&v"(R6), "=&v"(R7) \
    : "v"(src) : "memory")

// LLC-direct reload of slot J (exec-masked by the pend predicate)
#define RELOAD(J, UJ, OFS) \
  if (pend & (1 << J)){ \
    asm volatile("global_load_dwordx2 %0, %1, off offset:" OFS " sc0 sc1" \
                 : "=v"(UJ) : "v"(src) : "memory"); \
  }

__global__ void __launch_bounds__(NTHR, 1) lstm_kernel(
    const float* __restrict__ xin, const float* __restrict__ Wih,
    const float* __restrict__ Whh, const float* __restrict__ bih,
    const float* __restrict__ bhh, u64* __restrict__ chk,
    float* __restrict__ seqout)
{
  extern __shared__ char smem[];
  float* hlds = (float*)smem;                    // [2][2304] = 18432 B (padded h)
  float* pls  = (float*)(smem + 18432);          // [2][640]  =  5120 B partials
  float* bias = (float*)(smem + 23552);          // [32]

  const int tid  = threadIdx.x;
  const int blk  = blockIdx.x;
  const int e0   = blk << 3;                     // this block owns h elems e0..e0+7
  const int lane = tid & 63;
  const int wv   = tid >> 6;                     // wave 0..7, k-slice [wv*256, +256)
  const int rg   = lane >> 3;                    // row group: rows rg*4..rg*4+3
  const int ksl  = lane & 7;                     // 32-k sub-slice within wave
  const int ks   = (wv << 3) + ksl;              // global 32-k slice 0..63
  const int k0   = ks << 5;

  if (tid < 32){
    const int grow = ((tid >> 3) << 11) + e0 + (tid & 7);
    bias[tid] = bih[grow] + bhh[grow];
  }
  // x for t=0, written in the padded h layout
  for (int i = tid; i < 2 * E; i += NTHR){
    const int b = i >> 11, k = i & 2047;
    hlds[b * HLDS_B + (k >> 5) * 36 + (k & 31)] = xin[i];
  }
  __syncthreads();

  const float* hb0 = hlds + ks * 36;             // batch 0, own 32-k slice
  const float* hb1 = hlds + HLDS_B + ks * 36;    // batch 1

  // ---- fused: build f16 Wc = Wih + Whh into registers (64 half2) AND
  //      compute t=0 gates = x @ W_ih^T in full fp32 (h=0 at t=0) ----
  __half2 wh[64];
  float acc0[4] = {0.f, 0.f, 0.f, 0.f};
  float acc1[4] = {0.f, 0.f, 0.f, 0.f};
  #pragma unroll
  for (int rr = 0; rr < 4; ++rr){
    const int row  = (rg << 2) + rr;             // 0..31 = gate*8 + eoff
    const int grow = ((row >> 3) << 11) + e0 + (row & 7);
    const float* pa = Wih + (size_t)grow * E + k0;
    const float* pb = Whh + (size_t)grow * E + k0;
    #pragma unroll
    for (int c = 0; c < 8; ++c){                 // 4 k per chunk
      float4 a = *(const float4*)(pa + (c << 2));
      float4 b = *(const float4*)(pb + (c << 2));
      wh[(rr << 4) + (c << 1)    ] =
        __halves2half2(__float2half_rn(a.x + b.x), __float2half_rn(a.y + b.y));
      wh[(rr << 4) + (c << 1) + 1] =
        __halves2half2(__float2half_rn(a.z + b.z), __float2half_rn(a.w + b.w));
      float4 x0 = *(const float4*)(hb0 + (c << 2));
      float4 x1 = *(const float4*)(hb1 + (c << 2));
      acc0[rr] = fmaf(a.x, x0.x, acc0[rr]); acc0[rr] = fmaf(a.y, x0.y, acc0[rr]);
      acc0[rr] = fmaf(a.z, x0.z, acc0[rr]); acc0[rr] = fmaf(a.w, x0.w, acc0[rr]);
      acc1[rr] = fmaf(a.x, x1.x, acc1[rr]); acc1[rr] = fmaf(a.y, x1.y, acc1[rr]);
      acc1[rr] = fmaf(a.z, x1.z, acc1[rr]); acc1[rr] = fmaf(a.w, x1.w, acc1[rr]);
    }
  }

  const float br = bias[lane & 31];              // hoisted (used by wave 0)
  float creg = 0.0f;                             // cell state (producer lanes)

  // wave-local poll mapping: chunk c = wv*512 + j*64 + lane, so load j is a
  // 512 B contiguous wave read (full 64 B lines -> no fetch amplification).
  // chunk c (block-relative): b=(c>>3)&1, elem e=((c>>4)<<3)|(c&7)
  int cdst[8];
  #pragma unroll
  for (int j = 0; j < 8; ++j){
    const int c = (wv << 9) + (j << 6) + lane;
    const int b = (c >> 3) & 1;
    const int e = ((c >> 4) << 3) | (c & 7);
    cdst[j] = b * HLDS_B + (e >> 5) * 36 + (e & 31);
  }
  u64* const pchk0 = chk;                        // parity 0 base
  u64* const pchk1 = chk + 4096;                 // parity 1 base

  for (int t = 0; t < 2048; ++t){
    // wave-level pre-reduce across the 8 k-sub-slices (ksl = lane bits 0..2)
    #pragma unroll
    for (int m = 1; m <= 4; m <<= 1){
      #pragma unroll
      for (int rr = 0; rr < 4; ++rr){
        acc0[rr] += __shfl_xor(acc0[rr], m, 64);
        acc1[rr] += __shfl_xor(acc1[rr], m, 64);
      }
    }
    if (ksl == 0){                               // 8 lanes/wave publish partials
      float2* pw = (float2*)(pls + (t & 1) * PLS_PAR);
      #pragma unroll
      for (int rr = 0; rr < 4; ++rr)
        pw[((rg << 2) + rr) * (PLS_STRIDE / 2) + wv] = make_float2(acc0[rr], acc1[rr]);
    }
    __syncthreads();                             // the ONLY barrier per step

    if (wv == 0){                                // reduce 8 wave-partials + update
      const int r = lane & 31;
      const int b = lane >> 5;
      const float* rp = pls + (t & 1) * PLS_PAR + r * PLS_STRIDE;
      float4 v0 = *(const float4*)(rp);
      float4 v1 = *(const float4*)(rp + 4);
      float4 v2 = *(const float4*)(rp + 8);
      float4 v3 = *(const float4*)(rp + 12);
      float s = br + (b ? (v0.y + v0.w + v1.y + v1.w + v2.y + v2.w + v3.y + v3.w)
                        : (v0.x + v0.z + v1.x + v1.z + v2.x + v2.z + v3.x + v3.z));
      const float gi = s;
      const float gf = __shfl(s, (lane + 8)  & 63, 64);
      const float gg = __shfl(s, (lane + 16) & 63, 64);
      const float go = __shfl(s, (lane + 24) & 63, 64);
      if (r < 8){
        const float cn = sigf(gf) * creg + sigf(gi) * tanhfast(gg);
        const float hn = sigf(go) * tanhfast(cn);
        creg = cn;
        if (t < 2047){                           // publish FIRST (critical path)
          const u64 pk = ((u64)(u32)(t + 1) << 32) | (u64)__float_as_uint(hn);
          u64* dst = (((t + 1) & 1) ? pchk1 : pchk0) + (blk << 4) + (b << 3) + r;
          asm volatile("global_store_dwordx2 %0, %1, off sc0 sc1"
                       :: "v"(dst), "v"(pk) : "memory");
        }
        seqout[(((size_t)b << 11) + (size_t)t) * E + e0 + r] = hn;
      }
    }
    if (t == 2047) break;

    {                                            // v4 poll: LLC-direct + sleep
      const u64* src = (((t + 1) & 1) ? pchk1 : pchk0) + (wv << 9) + lane;
      const u32 tag = (u32)(t + 1);
      u64 a0_, a1_, a2_, a3_, a4_, a5_, a6_, a7_;
      ISSUE8(a0_, a1_, a2_, a3_, a4_, a5_, a6_, a7_);
      asm volatile("s_waitcnt vmcnt(0)" ::: "memory");
      int pend = 0xFF;
      while (true){
        POLLCHK(0, a0_) POLLCHK(1, a1_) POLLCHK(2, a2_) POLLCHK(3, a3_)
        POLLCHK(4, a4_) POLLCHK(5, a5_) POLLCHK(6, a6_) POLLCHK(7, a7_)
        if (pend == 0) break;
        __builtin_amdgcn_s_sleep(1);
        RELOAD(0, a0_, "0")    RELOAD(1, a1_, "512")
        RELOAD(2, a2_, "1024") RELOAD(3, a3_, "1536")
        RELOAD(4, a4_, "2048") RELOAD(5, a5_, "2560")
        RELOAD(6, a6_, "3072") RELOAD(7, a7_, "3584")
        asm volatile("s_waitcnt vmcnt(0)" ::: "memory");
      }
      // own ds_writes visible to all lanes of this wave (wave-synchronous)
      asm volatile("s_waitcnt lgkmcnt(0)" ::: "memory");
      __builtin_amdgcn_sched_barrier(0);
    }

    // compute acc(t+1): h @ Wc^T, weights in f16 registers
    #pragma unroll
    for (int rr = 0; rr < 4; ++rr){ acc0[rr] = 0.f; acc1[rr] = 0.f; }
    #pragma unroll
    for (int c8 = 0; c8 < 4; ++c8){              // 8 k per chunk
      float4 p0 = *(const float4*)(hb0 + (c8 << 3));
      float4 p1 = *(const float4*)(hb0 + (c8 << 3) + 4);
      float4 q0 = *(const float4*)(hb1 + (c8 << 3));
      float4 q1 = *(const float4*)(hb1 + (c8 << 3) + 4);
      #pragma unroll
      for (int rr = 0; rr < 4; ++rr){
        ROWFMA8(wh[(rr << 4) + (c8 << 2)],     wh[(rr << 4) + (c8 << 2) + 1],
                wh[(rr << 4) + (c8 << 2) + 2], wh[(rr << 4) + (c8 << 2) + 3],
                acc0[rr], acc1[rr]);
      }
    }
  }
}

// In-place projection: out[row][n] = sum_k h[row][k]*Wout[n][k] + bout[n].
// Block owns 16 rows (f32-staged to LDS). v10: 2 passes x 4 columns per
// thread: each pair of broadcast LDS b128 reads now feeds 32 FMAs (was 16)
// -> LDS issue halves (32768 -> 16384 b128/thread, the binding term per
// v9 post-mortem). 256 thr/block = 1 wave/SIMD -> 256-VGPR budget; ~120
// needed (64 acc + 32 weights + temps).
__global__ void __launch_bounds__(256, 1) proj_kernel(
    float* __restrict__ io, const float* __restrict__ Wout,
    const float* __restrict__ bout)
{
  extern __shared__ char smem[];
  float* alds = (float*)smem;                  // 16 x 2048 fp32 = 131072 B
  const int tid = threadIdx.x;
  const size_t rbase = (size_t)blockIdx.x * 16 * E;

  for (int idx = tid; idx < 8192; idx += 256){
    float4 v = *(const float4*)(io + rbase + ((size_t)idx << 2));
    *(float4*)(alds + (idx << 2)) = v;
  }
  __syncthreads();

  for (int p = 0; p < 2; ++p){
    const int n0 = (p << 10) + tid;            // 4 columns: n0 + {0,256,512,768}
    const int n1 = n0 + 256;
    const int n2 = n0 + 512;
    const int n3 = n0 + 768;
    const float* wr0 = Wout + (size_t)n0 * E;
    const float* wr1 = Wout + (size_t)n1 * E;
    const float* wr2 = Wout + (size_t)n2 * E;
    const float* wr3 = Wout + (size_t)n3 * E;
    float acc0[16], acc1[16], acc2[16], acc3[16];
    #pragma unroll
    for (int m = 0; m < 16; ++m){
      acc0[m] = 0.0f; acc1[m] = 0.0f; acc2[m] = 0.0f; acc3[m] = 0.0f;
    }
    for (int kc = 0; kc < 256; ++kc){          // 8 k per iter
      const float4 a0v = *(const float4*)(wr0 + (kc << 3));
      const float4 a1v = *(const float4*)(wr0 + (kc << 3) + 4);
      const float4 b0v = *(const float4*)(wr1 + (kc << 3));
      const float4 b1v = *(const float4*)(wr1 + (kc << 3) + 4);
      const float4 c0v = *(const float4*)(wr2 + (kc << 3));
      const float4 c1v = *(const float4*)(wr2 + (kc << 3) + 4);
      const float4 d0v = *(const float4*)(wr3 + (kc << 3));
      const float4 d1v = *(const float4*)(wr3 + (kc << 3) + 4);
      const float* ap = alds + (kc << 3);
      #pragma unroll
      for (int m = 0; m < 16; ++m){
        const float* a = ap + (m << 11);
        float4 x0 = *(const float4*)(a);       // broadcast: all lanes same addr
        float4 x1 = *(const float4*)(a + 4);
        acc0[m] = fmaf(a0v.x, x0.x, acc0[m]); acc0[m] = fmaf(a0v.y, x0.y, acc0[m]);
        acc0[m] = fmaf(a0v.z, x0.z, acc0[m]); acc0[m] = fmaf(a0v.w, x0.w, acc0[m]);
        acc0[m] = fmaf(a1v.x, x1.x, acc0[m]); acc0[m] = fmaf(a1v.y, x1.y, acc0[m]);
        acc0[m] = fmaf(a1v.z, x1.z, acc0[m]); acc0[m] = fmaf(a1v.w, x1.w, acc0[m]);
        acc1[m] = fmaf(b0v.x, x0.x, acc1[m]); acc1[m] = fmaf(b0v.y, x0.y, acc1[m]);
        acc1[m] = fmaf(b0v.z, x0.z, acc1[m]); acc1[m] = fmaf(b0v.w, x0.w, acc1[m]);
        acc1[m] = fmaf(b1v.x, x1.x, acc1[m]); acc1[m] = fmaf(b1v.y, x1.y, acc1[m]);
        acc1[m] = fmaf(b1v.z, x1.z, acc1[m]); acc1[m] = fmaf(b1v.w, x1.w, acc1[m]);
        acc2[m] = fmaf(c0v.x, x0.x, acc2[m]); acc2[m] = fmaf(c0v.y, x0.y, acc2[m]);
        acc2[m] = fmaf(c0v.z, x0.z, acc2[m]); acc2[m] = fmaf(c0v.w, x0.w, acc2[m]);
        acc2[m] = fmaf(c1v.x, x1.x, acc2[m]); acc2[m] = fmaf(c1v.y, x1.y, acc2[m]);
        acc2[m] = fmaf(c1v.z, x1.z, acc2[m]); acc2[m] = fmaf(c1v.w, x1.w, acc2[m]);
        acc3[m] = fmaf(d0v.x, x0.x, acc3[m]); acc3[m] = fmaf(d0v.y, x0.y, acc3[m]);
        acc3[m] = fmaf(d0v.z, x0.z, acc3[m]); acc3[m] = fmaf(d0v.w, x0.w, acc3[m]);
        acc3[m] = fmaf(d1v.x, x1.x, acc3[m]); acc3[m] = fmaf(d1v.y, x1.y, acc3[m]);
        acc3[m] = fmaf(d1v.z, x1.z, acc3[m]); acc3[m] = fmaf(d1v.w, x1.w, acc3[m]);
      }
    }
    const float bo0 = bout[n0];
    const float bo1 = bout[n1];
    const float bo2 = bout[n2];
    const float bo3 = bout[n3];
    #pragma unroll
    for (int m = 0; m < 16; ++m){
      io[rbase + ((size_t)m << 11) + n0] = acc0[m] + bo0;
      io[rbase + ((size_t)m << 11) + n1] = acc1[m] + bo1;
      io[rbase + ((size_t)m << 11) + n2] = acc2[m] + bo2;
      io[rbase + ((size_t)m << 11) + n3] = acc3[m] + bo3;
    }
  }
}

extern "C" void kernel_launch(void* const* d_in, const int* in_sizes, int n_in,
                              void* d_out, int out_size, void* d_ws, size_t ws_size,
                              hipStream_t stream)
{
  const float* xin  = (const float*)d_in[0];
  const float* Wih  = (const float*)d_in[1];
  const float* Whh  = (const float*)d_in[2];
  const float* bih  = (const float*)d_in[3];
  const float* bhh  = (const float*)d_in[4];
  const float* Wout = (const float*)d_in[5];
  const float* bout = (const float*)d_in[6];
  float* out = (float*)d_out;

  // chunk buffer: 2 parities x 4096 chunks x 8 B = 64 KB.
  // Poison 0xAAAAAAAA is never a valid tag (tags are 1..2047) -> no init pass.
  u64* chk = (u64*)d_ws;

  hipFuncSetAttribute((const void*)lstm_kernel,
                      hipFuncAttributeMaxDynamicSharedMemorySize, SMEM_MAIN);
  hipFuncSetAttribute((const void*)proj_kernel,
                      hipFuncAttributeMaxDynamicSharedMemorySize, SMEM_PROJ);

  void* args[] = { (void*)&xin, (void*)&Wih, (void*)&Whh, (void*)&bih, (void*)&bhh,
                   (void*)&chk, (void*)&out };
  hipLaunchCooperativeKernel((const void*)lstm_kernel, dim3(NBLK), dim3(NTHR),
                             args, SMEM_MAIN, stream);

  proj_kernel<<<256, 256, SMEM_PROJ, stream>>>(out, Wout, bout);
}